// Round 1
// baseline (78.203 us; speedup 1.0000x reference)
//
#include <hip/hip_runtime.h>
#include <float.h>

#define BATCH 16
#define CH 3
#define HH 256
#define WW 256
#define TW 32
#define TH 32
#define HALO 2
#define TILE_W (TW + 2 * HALO)    // 36 logical cols
#define TILE_H (TH + 2 * HALO)    // 36 rows
#define TILE_WP (TILE_W + 1)      // 37: padded float4 stride -> half-waves hit disjoint bank sets
#define BIGV 1e30f
#define NBLOCKS ((WW / TW) * (HH / TH) * BATCH)   // 1024

__global__ __launch_bounds__(256) void nnloss_kernel(
    const float* __restrict__ pred,
    const float* __restrict__ gt,
    float* __restrict__ partials)
{
    // gt tile with halo; 3 channels packed into float4 (w unused)
    __shared__ float4 tile[TILE_H * TILE_WP];   // 36*37*16 = 21312 B
    __shared__ float warp_sums[4];

    const int tid = threadIdx.x;
    const int w0 = blockIdx.x * TW;
    const int h0 = blockIdx.y * TH;
    const int b  = blockIdx.z;

    const int plane = HH * WW;                       // 65536, fits int32
    const float* __restrict__ gtb = gt  + (size_t)b * CH * plane;
    const float* __restrict__ prb = pred + (size_t)b * CH * plane;

    // ---- pred loads FIRST: overlap their HBM latency with gt staging + barrier ----
    const int tx = tid & 31;        // 0..31 (output col within tile)
    const int ty = tid >> 5;        // 0..7  -> rows ty*4 .. ty*4+3
    const int row_base = ty * 4;

    float p0[4], p1[4], p2[4];
    #pragma unroll
    for (int o = 0; o < 4; ++o) {
        const int off = (h0 + row_base + o) * WW + (w0 + tx);   // int32 offsets
        p0[o] = __builtin_nontemporal_load(&prb[off]);
        p1[o] = __builtin_nontemporal_load(&prb[off + plane]);
        p2[o] = __builtin_nontemporal_load(&prb[off + 2 * plane]);
    }

    // ---- stage gt tile (channels packed) ----
    for (int idx = tid; idx < TILE_H * TILE_W; idx += 256) {
        const int r   = idx / TILE_W;
        const int col = idx - r * TILE_W;
        const int gh = h0 + r - HALO;
        const int gw = w0 + col - HALO;
        float4 v = make_float4(BIGV, BIGV, BIGV, 0.0f);
        if ((unsigned)gh < HH && (unsigned)gw < WW) {
            const int o = gh * WW + gw;              // int32 offsets
            v.x = gtb[o];
            v.y = gtb[o + plane];
            v.z = gtb[o + 2 * plane];
        }
        tile[r * TILE_WP + col] = v;
    }
    __syncthreads();

    // ---- compute: each thread does a 4-row vertical strip ----
    float m[4];
    #pragma unroll
    for (int o = 0; o < 4; ++o) m[o] = FLT_MAX;

    // gt rows needed: row_base .. row_base+7 (tile coords); each read once,
    // reused for all output rows o with 0 <= k-o <= 4.
    // fmin reassociation over finite non-negative values is bit-exact, so this
    // loop order matches the previous kernel's results exactly.
    #pragma unroll
    for (int k = 0; k < 8; ++k) {
        const int tr = row_base + k;
        #pragma unroll
        for (int dj = 0; dj < 5; ++dj) {
            const float4 g = tile[tr * TILE_WP + tx + dj];
            #pragma unroll
            for (int o = 0; o < 4; ++o) {
                if (k - o >= 0 && k - o <= 4) {
                    const float s = fabsf(g.x - p0[o])
                                  + fabsf(g.y - p1[o])
                                  + fabsf(g.z - p2[o]);
                    m[o] = fminf(m[o], s);
                }
            }
        }
    }

    float local = m[0] + m[1] + m[2] + m[3];

    // ---- block reduction -> one partial per block (identical topology) ----
    #pragma unroll
    for (int off = 32; off > 0; off >>= 1)
        local += __shfl_down(local, off, 64);
    if ((tid & 63) == 0) warp_sums[tid >> 6] = local;
    __syncthreads();
    if (tid == 0) {
        const int bid = (blockIdx.z * gridDim.y + blockIdx.y) * gridDim.x + blockIdx.x;
        partials[bid] = warp_sums[0] + warp_sums[1] + warp_sums[2] + warp_sums[3];
    }
}

__global__ __launch_bounds__(256) void reduce_kernel(
    const float* __restrict__ partials, float* __restrict__ out)
{
    __shared__ float warp_sums[4];
    const int tid = threadIdx.x;
    float local = 0.0f;
    #pragma unroll
    for (int i = 0; i < NBLOCKS / 256; ++i)
        local += partials[i * 256 + tid];
    #pragma unroll
    for (int off = 32; off > 0; off >>= 1)
        local += __shfl_down(local, off, 64);
    if ((tid & 63) == 0) warp_sums[tid >> 6] = local;
    __syncthreads();
    if (tid == 0)
        out[0] = warp_sums[0] + warp_sums[1] + warp_sums[2] + warp_sums[3];
}

extern "C" void kernel_launch(void* const* d_in, const int* in_sizes, int n_in,
                              void* d_out, int out_size, void* d_ws, size_t ws_size,
                              hipStream_t stream) {
    const float* pred = (const float*)d_in[0];
    const float* gt   = (const float*)d_in[1];
    float* out = (float*)d_out;
    float* partials = (float*)d_ws;   // 1024 floats = 4 KB of the workspace

    dim3 grid(WW / TW, HH / TH, BATCH);   // 8 x 8 x 16 = 1024 blocks
    nnloss_kernel<<<grid, 256, 0, stream>>>(pred, gt, partials);
    reduce_kernel<<<1, 256, 0, stream>>>(partials, out);
}